// Round 2
// baseline (240.640 us; speedup 1.0000x reference)
//
#include <hip/hip_runtime.h>

#define B_ROWS 8192
#define DIN    1024
#define UNITS  1024
#define KTOT   2048   // DIN + UNITS
#define NCOLS  4096   // 4*UNITS
#define BM 128
#define BN 128
#define BK 64
#define NT (KTOT / BK)   // 32 k-tiles

typedef __attribute__((ext_vector_type(8))) short bf16x8;
typedef __attribute__((ext_vector_type(4))) float f32x4;
typedef __attribute__((ext_vector_type(4))) unsigned short u16x4;

#define AS1(p) ((const __attribute__((address_space(1))) void*)(p))
#define AS3(p) ((__attribute__((address_space(3))) void*)(p))

__device__ inline unsigned short f2bf(float v) {
  union { float f; unsigned int u; } un; un.f = v;
  unsigned int r = un.u + 0x7FFFu + ((un.u >> 16) & 1u);   // RNE
  return (unsigned short)(r >> 16);
}

__device__ inline float sigmoid_f(float x) { return 1.0f / (1.0f + __expf(-x)); }
__device__ inline float tanh_f(float x)    { return 1.0f - 2.0f / (1.0f + __expf(2.0f * x)); }

// ---------------- prep A: A_bf16[row][k] = masked x (k<1024) | masked h (k>=1024) ----
__global__ void prep_a_kernel(const float* __restrict__ x, const float* __restrict__ h,
                              const float* __restrict__ dp, const float* __restrict__ rdp,
                              unsigned short* __restrict__ A) {
  const int n4 = (B_ROWS * DIN) / 4;
  const float sc = 1.0f / 0.9f;
  for (int i = blockIdx.x * blockDim.x + threadIdx.x; i < n4; i += gridDim.x * blockDim.x) {
    float4 xv = reinterpret_cast<const float4*>(x)[i];
    float4 uv = reinterpret_cast<const float4*>(dp)[i];
    float4 hv = reinterpret_cast<const float4*>(h)[i];
    float4 rv = reinterpret_cast<const float4*>(rdp)[i];
    u16x4 xa, ha;
    xa.x = f2bf(uv.x >= 0.1f ? xv.x * sc : 0.0f);
    xa.y = f2bf(uv.y >= 0.1f ? xv.y * sc : 0.0f);
    xa.z = f2bf(uv.z >= 0.1f ? xv.z * sc : 0.0f);
    xa.w = f2bf(uv.w >= 0.1f ? xv.w * sc : 0.0f);
    ha.x = f2bf(rv.x >= 0.1f ? hv.x * sc : 0.0f);
    ha.y = f2bf(rv.y >= 0.1f ? hv.y * sc : 0.0f);
    ha.z = f2bf(rv.z >= 0.1f ? hv.z * sc : 0.0f);
    ha.w = f2bf(rv.w >= 0.1f ? hv.w * sc : 0.0f);
    int e = i * 4;
    int row = e >> 10;
    int col = e & 1023;
    *reinterpret_cast<u16x4*>(&A[(size_t)row * KTOT + col]) = xa;
    *reinterpret_cast<u16x4*>(&A[(size_t)row * KTOT + DIN + col]) = ha;
  }
}

// ---------------- prep B: Bt[n][k] (bf16, N-major) with gate-interleave permutation ---
// source col c = g*1024 + m  ->  n = (m>>5)*128 + g*32 + (m&31)
__global__ void prep_b_kernel(const float* __restrict__ kern, const float* __restrict__ rkern,
                              const float* __restrict__ kdp, const float* __restrict__ rkdp,
                              unsigned short* __restrict__ Bt) {
  __shared__ float tile[32][33];
  const int c0 = blockIdx.x * 32;
  const int k0 = blockIdx.y * 32;
  const float sc = 1.0f / 0.95f;
  const float* W; const float* U; int kr;
  if (k0 < DIN) { W = kern;  U = kdp;  kr = k0; }
  else          { W = rkern; U = rkdp; kr = k0 - DIN; }
  const int tx = threadIdx.x, ty = threadIdx.y;
  #pragma unroll
  for (int i = 0; i < 4; ++i) {
    int kk = ty + i * 8;
    size_t off = (size_t)(kr + kk) * NCOLS + c0 + tx;
    float wv = W[off];
    float uv = U[off];
    tile[kk][tx] = (uv >= 0.05f) ? wv * sc : 0.0f;
  }
  __syncthreads();
  const int g  = c0 >> 10;
  const int m0 = c0 & 1023;              // 32-aligned
  const int n0 = (m0 >> 5) * 128 + g * 32;
  #pragma unroll
  for (int i = 0; i < 4; ++i) {
    int cc = ty + i * 8;
    Bt[(size_t)(n0 + cc) * KTOT + k0 + tx] = f2bf(tile[tx][cc]);
  }
}

// ---------------- fused GEMM + LSTM epilogue ----------------------------------------
__launch_bounds__(256, 2)
__global__ void lstm_gemm_kernel(const unsigned short* __restrict__ A,
                                 const unsigned short* __restrict__ Bt,
                                 const float* __restrict__ bias,
                                 const float* __restrict__ c_in,
                                 float* __restrict__ out_h,
                                 float* __restrict__ out_c) {
  __shared__ __align__(16) unsigned char smem[67584];   // staging 64KB / z-tile 128x132 f32

  const int tid  = threadIdx.x;
  const int lane = tid & 63;
  const int wid  = tid >> 6;
  const int wr   = wid >> 1;     // wave row (0..1)
  const int wc   = wid & 1;      // wave col (0..1)
  const int bm   = blockIdx.x >> 5;   // 64 row-blocks
  const int bn   = blockIdx.x & 31;   // 32 col-blocks (unit blocks)
  const int brow = bm * BM;
  const int bnrow = bn * BN;     // base row in Bt

  f32x4 acc[4][4];
  const f32x4 zero4 = {0.0f, 0.0f, 0.0f, 0.0f};
  #pragma unroll
  for (int i = 0; i < 4; ++i)
    #pragma unroll
    for (int j = 0; j < 4; ++j) acc[i][j] = zero4;

  auto stage = [&](int buf, int kt) {
    unsigned char* Asb = smem + buf * 32768;
    unsigned char* Bsb = smem + 16384 + buf * 32768;
    const int k0 = kt * BK;
    #pragma unroll
    for (int j = 0; j < 4; ++j) {
      int e   = wid * 2048 + j * 512 + lane * 8;  // element in [128][64]
      int row = e >> 6;
      int col = e & 63;
      const unsigned short* gA = A  + (size_t)(brow  + row) * KTOT + k0 + col;
      const unsigned short* gB = Bt + (size_t)(bnrow + row) * KTOT + k0 + col;
      __builtin_amdgcn_global_load_lds(AS1(gA), AS3(Asb + wid * 4096 + j * 1024), 16, 0, 0);
      __builtin_amdgcn_global_load_lds(AS1(gB), AS3(Bsb + wid * 4096 + j * 1024), 16, 0, 0);
    }
  };

  auto compute = [&](int buf) {
    const unsigned short* as = (const unsigned short*)(smem + buf * 32768);
    const unsigned short* bs = (const unsigned short*)(smem + 16384 + buf * 32768);
    const int r15 = lane & 15;
    const int kh  = lane >> 4;
    #pragma unroll
    for (int ks = 0; ks < 2; ++ks) {
      bf16x8 af[4], bfv[4];
      #pragma unroll
      for (int f = 0; f < 4; ++f)
        af[f] = *reinterpret_cast<const bf16x8*>(&as[(wr * 64 + f * 16 + r15) * 64 + ks * 32 + kh * 8]);
      #pragma unroll
      for (int f = 0; f < 4; ++f)
        bfv[f] = *reinterpret_cast<const bf16x8*>(&bs[(wc * 64 + f * 16 + r15) * 64 + ks * 32 + kh * 8]);
      #pragma unroll
      for (int i = 0; i < 4; ++i)
        #pragma unroll
        for (int j = 0; j < 4; ++j)
          acc[i][j] = __builtin_amdgcn_mfma_f32_16x16x32_bf16(af[i], bfv[j], acc[i][j], 0, 0, 0);
    }
  };

  stage(0, 0);
  __syncthreads();
  int cur = 0;
  for (int kt = 0; kt < NT; ++kt) {
    if (kt + 1 < NT) stage(cur ^ 1, kt + 1);
    compute(cur);
    __syncthreads();
    cur ^= 1;
  }

  // ---- epilogue: acc -> LDS z-tile, then gate math ----
  float* zs = reinterpret_cast<float*>(smem);
  const int ZLD = 132;
  #pragma unroll
  for (int i = 0; i < 4; ++i) {
    int row0 = wr * 64 + i * 16 + (lane >> 4) * 4;
    #pragma unroll
    for (int j = 0; j < 4; ++j) {
      int col = wc * 64 + j * 16 + (lane & 15);
      #pragma unroll
      for (int r = 0; r < 4; ++r)
        zs[(row0 + r) * ZLD + col] = acc[i][j][r];
    }
  }
  __syncthreads();

  const int u = tid & 31;
  const int rbase = (tid >> 5) * 16;
  const int unit = bn * 32 + u;
  const float b0 = bias[unit];
  const float b1 = bias[1024 + unit];
  const float b2 = bias[2048 + unit];
  const float b3 = bias[3072 + unit];
  #pragma unroll 4
  for (int r = 0; r < 16; ++r) {
    int row = rbase + r;
    size_t gidx = (size_t)(brow + row) * UNITS + unit;
    float zi = zs[row * ZLD +      u] + b0;
    float zf = zs[row * ZLD + 32 + u] + b1;
    float zc = zs[row * ZLD + 64 + u] + b2;
    float zo = zs[row * ZLD + 96 + u] + b3;
    float ig = sigmoid_f(zi);
    float fg = sigmoid_f(zf);
    float gg = tanh_f(zc);
    float og = sigmoid_f(zo);
    float cn = fg * c_in[gidx] + ig * gg;
    float hn = og * tanh_f(cn);
    out_h[gidx] = hn;
    out_c[gidx] = cn;
  }
}

extern "C" void kernel_launch(void* const* d_in, const int* in_sizes, int n_in,
                              void* d_out, int out_size, void* d_ws, size_t ws_size,
                              hipStream_t stream) {
  const float* x     = (const float*)d_in[0];
  const float* h     = (const float*)d_in[1];
  const float* c     = (const float*)d_in[2];
  const float* kern  = (const float*)d_in[3];
  const float* rkern = (const float*)d_in[4];
  const float* bias  = (const float*)d_in[5];
  const float* dp    = (const float*)d_in[6];
  const float* rdp   = (const float*)d_in[7];
  const float* kdp   = (const float*)d_in[8];
  const float* rkdp  = (const float*)d_in[9];

  unsigned short* Abf  = (unsigned short*)d_ws;                       // 8192*2048 bf16 = 32MB
  unsigned short* Btbf = Abf + (size_t)B_ROWS * KTOT;                 // 4096*2048 bf16 = 16MB

  float* out_h = (float*)d_out;
  float* out_c = out_h + (size_t)B_ROWS * UNITS;

  prep_a_kernel<<<2048, 256, 0, stream>>>(x, h, dp, rdp, Abf);
  prep_b_kernel<<<dim3(128, 64), dim3(32, 8), 0, stream>>>(kern, rkern, kdp, rkdp, Btbf);
  lstm_gemm_kernel<<<2048, 256, 0, stream>>>(Abf, Btbf, bias, c, out_h, out_c);
}

// Round 3
// 204.621 us; speedup vs baseline: 1.1760x; 1.1760x over previous
//
#include <hip/hip_runtime.h>

#define B_ROWS 8192
#define DIN    1024
#define UNITS  1024
#define KTOT   2048   // DIN + UNITS
#define NCOLS  4096   // 4*UNITS
#define BM 128
#define BN 128
#define BK 64
#define NT (KTOT / BK)   // 32 k-tiles

typedef __attribute__((ext_vector_type(8))) short bf16x8;
typedef __attribute__((ext_vector_type(4))) float f32x4;
typedef __attribute__((ext_vector_type(4))) unsigned short u16x4;

#define AS1(p) ((const __attribute__((address_space(1))) void*)(p))
#define AS3(p) ((__attribute__((address_space(3))) void*)(p))

__device__ inline unsigned short f2bf(float v) {
  union { float f; unsigned int u; } un; un.f = v;
  unsigned int r = un.u + 0x7FFFu + ((un.u >> 16) & 1u);   // RNE
  return (unsigned short)(r >> 16);
}

// XOR-swizzle within each 64-element K-tile: bits 3-5 of the column XORed
// with (row & 7). Involution; baked into the STORED layout by the prep
// kernels so the GEMM's global_load_lds stays linear (rule #21) and only
// the ds_read applies the same XOR.
__device__ inline int swz_col(int c, int r) {
  return (c & ~63) | ((c & 63) ^ ((r & 7) << 3));
}

__device__ inline float sigmoid_f(float x) { return 1.0f / (1.0f + __expf(-x)); }
__device__ inline float tanh_f(float x)    { return 1.0f - 2.0f / (1.0f + __expf(2.0f * x)); }

// ---------------- prep A: A_bf16[row][k] = masked x (k<1024) | masked h (k>=1024) ----
// stored column swizzled per swz_col (DIN is a multiple of 64 so the h-half
// swizzles identically with its local column).
__global__ void prep_a_kernel(const float* __restrict__ x, const float* __restrict__ h,
                              const float* __restrict__ dp, const float* __restrict__ rdp,
                              unsigned short* __restrict__ A) {
  const int n4 = (B_ROWS * DIN) / 4;
  const float sc = 1.0f / 0.9f;
  for (int i = blockIdx.x * blockDim.x + threadIdx.x; i < n4; i += gridDim.x * blockDim.x) {
    float4 xv = reinterpret_cast<const float4*>(x)[i];
    float4 uv = reinterpret_cast<const float4*>(dp)[i];
    float4 hv = reinterpret_cast<const float4*>(h)[i];
    float4 rv = reinterpret_cast<const float4*>(rdp)[i];
    u16x4 xa, ha;
    xa.x = f2bf(uv.x >= 0.1f ? xv.x * sc : 0.0f);
    xa.y = f2bf(uv.y >= 0.1f ? xv.y * sc : 0.0f);
    xa.z = f2bf(uv.z >= 0.1f ? xv.z * sc : 0.0f);
    xa.w = f2bf(uv.w >= 0.1f ? xv.w * sc : 0.0f);
    ha.x = f2bf(rv.x >= 0.1f ? hv.x * sc : 0.0f);
    ha.y = f2bf(rv.y >= 0.1f ? hv.y * sc : 0.0f);
    ha.z = f2bf(rv.z >= 0.1f ? hv.z * sc : 0.0f);
    ha.w = f2bf(rv.w >= 0.1f ? hv.w * sc : 0.0f);
    int e = i * 4;
    int row = e >> 10;
    int col = e & 1023;
    int csw = swz_col(col, row);   // 4-aligned groups preserved (XOR hits bits 3-5)
    *reinterpret_cast<u16x4*>(&A[(size_t)row * KTOT + csw]) = xa;
    *reinterpret_cast<u16x4*>(&A[(size_t)row * KTOT + DIN + csw]) = ha;
  }
}

// ---------------- prep B: Bt[n][k] (bf16, N-major), 16-unit gate interleave ---------
// source col c = g*1024 + m  ->  n = (m>>4)*64 + g*16 + (m&15)
// so one wave's 64-col span holds all 4 gates of 16 units -> in-register epilogue.
// k column stored swizzled per swz_col(n).
__global__ void prep_b_kernel(const float* __restrict__ kern, const float* __restrict__ rkern,
                              const float* __restrict__ kdp, const float* __restrict__ rkdp,
                              unsigned short* __restrict__ Bt) {
  __shared__ float tile[32][33];
  const int c0 = blockIdx.x * 32;
  const int k0 = blockIdx.y * 32;
  const float sc = 1.0f / 0.95f;
  const float* W; const float* U; int kr;
  if (k0 < DIN) { W = kern;  U = kdp;  kr = k0; }
  else          { W = rkern; U = rkdp; kr = k0 - DIN; }
  const int tx = threadIdx.x, ty = threadIdx.y;
  #pragma unroll
  for (int i = 0; i < 4; ++i) {
    int kk = ty + i * 8;
    size_t off = (size_t)(kr + kk) * NCOLS + c0 + tx;
    float wv = W[off];
    float uv = U[off];
    tile[kk][tx] = (uv >= 0.05f) ? wv * sc : 0.0f;
  }
  __syncthreads();
  const int g  = c0 >> 10;
  const int m0 = c0 & 1023;              // 16-aligned, 32 wide
  #pragma unroll
  for (int i = 0; i < 4; ++i) {
    int cc = ty + i * 8;
    int m = m0 + cc;
    int n = (m >> 4) * 64 + g * 16 + (m & 15);
    int kst = swz_col(k0 + tx, n);
    Bt[(size_t)n * KTOT + kst] = f2bf(tile[tx][cc]);
  }
}

// ---------------- fused GEMM + in-register LSTM epilogue ----------------------------
__launch_bounds__(256, 2)
__global__ void lstm_gemm_kernel(const unsigned short* __restrict__ A,
                                 const unsigned short* __restrict__ Bt,
                                 const float* __restrict__ bias,
                                 const float* __restrict__ c_in,
                                 float* __restrict__ out_h,
                                 float* __restrict__ out_c) {
  __shared__ __align__(16) unsigned char smem[65536];   // 2 bufs x (A 16KB + B 16KB)

  const int tid  = threadIdx.x;
  const int lane = tid & 63;
  const int wid  = tid >> 6;
  const int wr   = wid >> 1;     // wave row (0..1)
  const int wc   = wid & 1;      // wave col (0..1)
  const int bm   = blockIdx.x >> 5;   // 64 row-blocks
  const int bn   = blockIdx.x & 31;   // 32 col-blocks
  const int brow = bm * BM;
  const int bnrow = bn * BN;     // base row in Bt

  f32x4 acc[4][4];
  const f32x4 zero4 = {0.0f, 0.0f, 0.0f, 0.0f};
  #pragma unroll
  for (int i = 0; i < 4; ++i)
    #pragma unroll
    for (int j = 0; j < 4; ++j) acc[i][j] = zero4;

  auto stage = [&](int buf, int kt) {
    unsigned char* Asb = smem + buf * 32768;
    unsigned char* Bsb = smem + 16384 + buf * 32768;
    const int k0 = kt * BK;
    #pragma unroll
    for (int j = 0; j < 4; ++j) {
      int e   = wid * 2048 + j * 512 + lane * 8;  // element in [128][64]
      int row = e >> 6;
      int col = e & 63;
      const unsigned short* gA = A  + (size_t)(brow  + row) * KTOT + k0 + col;
      const unsigned short* gB = Bt + (size_t)(bnrow + row) * KTOT + k0 + col;
      __builtin_amdgcn_global_load_lds(AS1(gA), AS3(Asb + wid * 4096 + j * 1024), 16, 0, 0);
      __builtin_amdgcn_global_load_lds(AS1(gB), AS3(Bsb + wid * 4096 + j * 1024), 16, 0, 0);
    }
  };

  const int r15 = lane & 15;
  const int kh  = lane >> 4;            // 0..3
  const int sw  = (r15 & 7) << 3;       // read-side XOR (elements)

  auto compute = [&](int buf) {
    const unsigned short* as = (const unsigned short*)(smem + buf * 32768);
    const unsigned short* bs = (const unsigned short*)(smem + 16384 + buf * 32768);
    #pragma unroll
    for (int ks = 0; ks < 2; ++ks) {
      const int colk = (ks * 32 + kh * 8) ^ sw;
      bf16x8 af[4], bfv[4];
      #pragma unroll
      for (int f = 0; f < 4; ++f)
        af[f] = *reinterpret_cast<const bf16x8*>(&as[(wr * 64 + f * 16 + r15) * 64 + colk]);
      #pragma unroll
      for (int f = 0; f < 4; ++f)
        bfv[f] = *reinterpret_cast<const bf16x8*>(&bs[(wc * 64 + f * 16 + r15) * 64 + colk]);
      #pragma unroll
      for (int i = 0; i < 4; ++i)
        #pragma unroll
        for (int j = 0; j < 4; ++j)
          acc[i][j] = __builtin_amdgcn_mfma_f32_16x16x32_bf16(af[i], bfv[j], acc[i][j], 0, 0, 0);
    }
  };

  stage(0, 0);
  __syncthreads();
  int cur = 0;
  for (int kt = 0; kt < NT; ++kt) {
    if (kt + 1 < NT) stage(cur ^ 1, kt + 1);
    compute(cur);
    __syncthreads();
    cur ^= 1;
  }

  // ---- in-register epilogue: acc[i][g] holds gate g of unit (wc*16 + lane&15) ----
  const int q    = lane >> 4;                    // 0..3 row quarter
  const int unit = bn * 32 + wc * 16 + (lane & 15);
  const float b0 = bias[unit];
  const float b1 = bias[1024 + unit];
  const float b2 = bias[2048 + unit];
  const float b3 = bias[3072 + unit];
  #pragma unroll
  for (int i = 0; i < 4; ++i) {
    const int row0 = brow + wr * 64 + i * 16 + q * 4;
    #pragma unroll
    for (int r = 0; r < 4; ++r) {
      size_t gidx = (size_t)(row0 + r) * UNITS + unit;
      float zi = acc[i][0][r] + b0;
      float zf = acc[i][1][r] + b1;
      float zc = acc[i][2][r] + b2;
      float zo = acc[i][3][r] + b3;
      float ig = sigmoid_f(zi);
      float fg = sigmoid_f(zf);
      float gg = tanh_f(zc);
      float og = sigmoid_f(zo);
      float cn = fg * c_in[gidx] + ig * gg;
      float hn = og * tanh_f(cn);
      out_h[gidx] = hn;
      out_c[gidx] = cn;
    }
  }
}

extern "C" void kernel_launch(void* const* d_in, const int* in_sizes, int n_in,
                              void* d_out, int out_size, void* d_ws, size_t ws_size,
                              hipStream_t stream) {
  const float* x     = (const float*)d_in[0];
  const float* h     = (const float*)d_in[1];
  const float* c     = (const float*)d_in[2];
  const float* kern  = (const float*)d_in[3];
  const float* rkern = (const float*)d_in[4];
  const float* bias  = (const float*)d_in[5];
  const float* dp    = (const float*)d_in[6];
  const float* rdp   = (const float*)d_in[7];
  const float* kdp   = (const float*)d_in[8];
  const float* rkdp  = (const float*)d_in[9];

  unsigned short* Abf  = (unsigned short*)d_ws;                       // 8192*2048 bf16 = 32MB
  unsigned short* Btbf = Abf + (size_t)B_ROWS * KTOT;                 // 4096*2048 bf16 = 16MB

  float* out_h = (float*)d_out;
  float* out_c = out_h + (size_t)B_ROWS * UNITS;

  prep_a_kernel<<<2048, 256, 0, stream>>>(x, h, dp, rdp, Abf);
  prep_b_kernel<<<dim3(128, 64), dim3(32, 8), 0, stream>>>(kern, rkern, kdp, rkdp, Btbf);
  lstm_gemm_kernel<<<2048, 256, 0, stream>>>(Abf, Btbf, bias, c, out_h, out_c);
}

// Round 4
// 194.543 us; speedup vs baseline: 1.2370x; 1.0518x over previous
//
#include <hip/hip_runtime.h>

#define B_ROWS 8192
#define DIN    1024
#define UNITS  1024
#define KTOT   2048   // DIN + UNITS
#define NCOLS  4096   // 4*UNITS
#define BM 256
#define BN 256
#define BK 64
#define NT (KTOT / BK)    // 32 K-tiles
#define NITER (NT / 2)    // 16 iterations, 2 K-tiles each

typedef __attribute__((ext_vector_type(8))) short bf16x8;
typedef __attribute__((ext_vector_type(4))) float f32x4;
typedef __attribute__((ext_vector_type(4))) unsigned short u16x4;

#define AS1(p) ((const __attribute__((address_space(1))) void*)(p))
#define AS3(p) ((__attribute__((address_space(3))) void*)(p))

__device__ inline unsigned short f2bf(float v) {
  union { float f; unsigned int u; } un; un.f = v;
  unsigned int r = un.u + 0x7FFFu + ((un.u >> 16) & 1u);   // RNE
  return (unsigned short)(r >> 16);
}

// XOR-swizzle within each 64-element K-tile group, baked into the STORED
// global layout (rule #21: global_load_lds stays linear; ds_read applies
// the same XOR).
__device__ inline int swz_col(int c, int r) {
  return (c & ~63) | ((c & 63) ^ ((r & 7) << 3));
}

__device__ inline float sigmoid_f(float x) { return 1.0f / (1.0f + __expf(-x)); }
__device__ inline float tanh_f(float x)    { return 1.0f - 2.0f / (1.0f + __expf(2.0f * x)); }

// ---------------- prep A: A_bf16[row][k] = masked x (k<1024) | masked h (k>=1024) ----
__global__ void prep_a_kernel(const float* __restrict__ x, const float* __restrict__ h,
                              const float* __restrict__ dp, const float* __restrict__ rdp,
                              unsigned short* __restrict__ A) {
  const int n4 = (B_ROWS * DIN) / 4;
  const float sc = 1.0f / 0.9f;
  for (int i = blockIdx.x * blockDim.x + threadIdx.x; i < n4; i += gridDim.x * blockDim.x) {
    float4 xv = reinterpret_cast<const float4*>(x)[i];
    float4 uv = reinterpret_cast<const float4*>(dp)[i];
    float4 hv = reinterpret_cast<const float4*>(h)[i];
    float4 rv = reinterpret_cast<const float4*>(rdp)[i];
    u16x4 xa, ha;
    xa.x = f2bf(uv.x >= 0.1f ? xv.x * sc : 0.0f);
    xa.y = f2bf(uv.y >= 0.1f ? xv.y * sc : 0.0f);
    xa.z = f2bf(uv.z >= 0.1f ? xv.z * sc : 0.0f);
    xa.w = f2bf(uv.w >= 0.1f ? xv.w * sc : 0.0f);
    ha.x = f2bf(rv.x >= 0.1f ? hv.x * sc : 0.0f);
    ha.y = f2bf(rv.y >= 0.1f ? hv.y * sc : 0.0f);
    ha.z = f2bf(rv.z >= 0.1f ? hv.z * sc : 0.0f);
    ha.w = f2bf(rv.w >= 0.1f ? hv.w * sc : 0.0f);
    int e = i * 4;
    int row = e >> 10;
    int col = e & 1023;
    int csw = swz_col(col, row);
    *reinterpret_cast<u16x4*>(&A[(size_t)row * KTOT + csw]) = xa;
    *reinterpret_cast<u16x4*>(&A[(size_t)row * KTOT + DIN + csw]) = ha;
  }
}

// ---------------- prep B: Bt[n][k] (bf16, N-major), 64-unit gate interleave ---------
// source col c = g*1024 + m  ->  n = (m>>6)*256 + g*64 + (m&63)
// One 256-wide block-col holds all 4 gates of 64 units; within it a wave's
// 64-col span (g*64 + wn*16 + r15) holds gate g of unit bn*64+wn*16+r15.
__global__ void prep_b_kernel(const float* __restrict__ kern, const float* __restrict__ rkern,
                              const float* __restrict__ kdp, const float* __restrict__ rkdp,
                              unsigned short* __restrict__ Bt) {
  __shared__ float tile[32][33];
  const int c0 = blockIdx.x * 32;
  const int k0 = blockIdx.y * 32;
  const float sc = 1.0f / 0.95f;
  const float* W; const float* U; int kr;
  if (k0 < DIN) { W = kern;  U = kdp;  kr = k0; }
  else          { W = rkern; U = rkdp; kr = k0 - DIN; }
  const int tx = threadIdx.x, ty = threadIdx.y;
  #pragma unroll
  for (int i = 0; i < 4; ++i) {
    int kk = ty + i * 8;
    size_t off = (size_t)(kr + kk) * NCOLS + c0 + tx;
    float wv = W[off];
    float uv = U[off];
    tile[kk][tx] = (uv >= 0.05f) ? wv * sc : 0.0f;
  }
  __syncthreads();
  const int g  = c0 >> 10;
  const int m0 = c0 & 1023;
  #pragma unroll
  for (int i = 0; i < 4; ++i) {
    int cc = ty + i * 8;
    int m = m0 + cc;
    int n = (m >> 6) * 256 + g * 64 + (m & 63);
    int kst = swz_col(k0 + tx, n);
    Bt[(size_t)n * KTOT + kst] = f2bf(tile[tx][cc]);
  }
}

// ---------------- 256x256 8-phase GEMM + in-register LSTM epilogue ------------------
// LDS map (128 KiB): buf b in {0,1}: A[256][64]bf16 @ b*65536, B[256][64] @ b*65536+32768.
// Phase schedule per iteration t (tiles 2t from buf0, 2t+1 from buf1):
//  P1 rd A0,B0(buf0) | stage B1^buf1(2t+1) | MFMA q(0,0)
//  P2 rd B1(buf0)    | stage A1^buf1(2t+1) | MFMA q(0,1)
//  P3 rd A1(buf0)    | stage A0^buf0(2t+2) | MFMA q(1,0)
//  P4 -              | stage B0^buf0(2t+2) | MFMA q(1,1) | vmcnt(4)
//  P5 rd A0,B0(buf1) | stage A1^buf0(2t+2) | MFMA q(0,0)
//  P6 rd B1(buf1)    | stage B1^buf0(2t+2) | MFMA q(0,1)
//  P7 rd A1(buf1)    | stage A0^buf1(2t+3) | MFMA q(1,0)
//  P8 -              | stage B0^buf1(2t+3) | MFMA q(1,1) | vmcnt(4)
// Every stage targets a half dead as of the previous barrier; every read is
// covered by the preceding counted vmcnt (hand-verified both directions).

#define FENCE() asm volatile("" ::: "memory")
#define SBAR()  do { FENCE(); __builtin_amdgcn_s_barrier(); FENCE(); } while (0)

#define LOAD_A(BUF, MH) do { \
  const unsigned short* as_ = (const unsigned short*)(smem + (BUF) * 65536); \
  _Pragma("unroll") for (int f_ = 0; f_ < 4; ++f_) { \
    const int row_ = ((MH) * 4 + f_) * 32 + wm * 16 + r15; \
    _Pragma("unroll") for (int ks_ = 0; ks_ < 2; ++ks_) \
      a[f_ * 2 + ks_] = *(const bf16x8*)(&as_[row_ * 64 + ((ks_ * 32 + kh * 8) ^ sw)]); \
  } } while (0)

#define LOAD_B(BUF, NH) do { \
  const unsigned short* bs_ = (const unsigned short*)(smem + (BUF) * 65536 + 32768); \
  _Pragma("unroll") for (int g_ = 0; g_ < 2; ++g_) { \
    const int row_ = ((NH) * 2 + g_) * 64 + wn * 16 + r15; \
    _Pragma("unroll") for (int ks_ = 0; ks_ < 2; ++ks_) \
      b[((NH) * 2 + g_) * 2 + ks_] = *(const bf16x8*)(&bs_[row_ * 64 + ((ks_ * 32 + kh * 8) ^ sw)]); \
  } } while (0)

#define MMA_QUAD(MH, NH) do { \
  __builtin_amdgcn_s_setprio(1); \
  _Pragma("unroll") for (int f_ = 0; f_ < 4; ++f_) \
    _Pragma("unroll") for (int g_ = 0; g_ < 2; ++g_) \
      _Pragma("unroll") for (int ks_ = 0; ks_ < 2; ++ks_) \
        acc[(MH) * 4 + f_][(NH) * 2 + g_] = __builtin_amdgcn_mfma_f32_16x16x32_bf16( \
            a[f_ * 2 + ks_], b[((NH) * 2 + g_) * 2 + ks_], acc[(MH) * 4 + f_][(NH) * 2 + g_], 0, 0, 0); \
  __builtin_amdgcn_s_setprio(0); \
  } while (0)

__global__ __launch_bounds__(512, 2) void lstm_gemm_kernel(
    const unsigned short* __restrict__ A,
    const unsigned short* __restrict__ Bt,
    const float* __restrict__ bias,
    const float* __restrict__ c_in,
    float* __restrict__ out_h,
    float* __restrict__ out_c) {
  __shared__ __align__(16) unsigned char smem[131072];

  const int tid  = threadIdx.x;
  const int lane = tid & 63;
  const int wid  = tid >> 6;     // 0..7
  const int wm   = wid & 1;      // M-wave (16-row interleave)
  const int wn   = wid >> 1;     // 0..3  (16-col interleave)
  const int bm   = blockIdx.x >> 4;   // 32 row-blocks
  const int bn   = blockIdx.x & 15;   // 16 col-blocks
  const int brow = bm * BM;
  const int bnrow = bn * BN;
  const int r15  = lane & 15;
  const int kh   = lane >> 4;
  const int sw   = (r15 & 7) << 3;

  f32x4 acc[8][4];
  const f32x4 zero4 = {0.0f, 0.0f, 0.0f, 0.0f};
  #pragma unroll
  for (int i = 0; i < 8; ++i)
    #pragma unroll
    for (int j = 0; j < 4; ++j) acc[i][j] = zero4;
  bf16x8 a[8], b[8];

  // one stage = one 16KB half-tile = 2 x global_load_lds(16B) per thread
  auto stageA = [&](int buf, int half, int kt) {
    if (kt >= NT) return;
    const int k0 = kt * BK;
    #pragma unroll
    for (int r = 0; r < 2; ++r) {
      const int rowb = half * 128 + r * 64 + wid * 8;   // wave-uniform
      const unsigned short* g = A + (size_t)(brow + rowb + (lane >> 3)) * KTOT + k0 + (lane & 7) * 8;
      __builtin_amdgcn_global_load_lds(AS1(g), AS3(smem + buf * 65536 + rowb * 128), 16, 0, 0);
    }
  };
  auto stageB = [&](int buf, int half, int kt) {
    if (kt >= NT) return;
    const int k0 = kt * BK;
    #pragma unroll
    for (int r = 0; r < 2; ++r) {
      const int rowb = half * 128 + r * 64 + wid * 8;
      const unsigned short* g = Bt + (size_t)(bnrow + rowb + (lane >> 3)) * KTOT + k0 + (lane & 7) * 8;
      __builtin_amdgcn_global_load_lds(AS1(g), AS3(smem + buf * 65536 + 32768 + rowb * 128), 16, 0, 0);
    }
  };

  // prologue: tile0 -> buf0 (4 halves), tile1 A0,B0 -> buf1
  stageA(0, 0, 0); stageA(0, 1, 0); stageB(0, 0, 0); stageB(0, 1, 0);
  stageA(1, 0, 1); stageB(1, 0, 1);
  asm volatile("s_waitcnt vmcnt(4)" ::: "memory");
  __builtin_amdgcn_sched_barrier(0);
  SBAR();

  #pragma unroll 1
  for (int t = 0; t < NITER; ++t) {
    const int kx = 2 * t + 2;      // next buf0 tile
    const int ky = 2 * t + 3;      // next buf1 tile
    const int kyc = 2 * t + 1;     // buf1 tile consumed this iteration
    // P1
    LOAD_A(0, 0); LOAD_B(0, 0);
    stageB(1, 1, kyc);
    SBAR();
    MMA_QUAD(0, 0);
    SBAR();
    // P2
    LOAD_B(0, 1);
    stageA(1, 1, kyc);
    SBAR();
    MMA_QUAD(0, 1);
    SBAR();
    // P3
    LOAD_A(0, 1);
    stageA(0, 0, kx);
    SBAR();
    MMA_QUAD(1, 0);
    SBAR();
    // P4
    stageB(0, 0, kx);
    SBAR();
    MMA_QUAD(1, 1);
    if (t < NITER - 1) { asm volatile("s_waitcnt vmcnt(4)" ::: "memory"); }
    else               { asm volatile("s_waitcnt vmcnt(0)" ::: "memory"); }
    __builtin_amdgcn_sched_barrier(0);
    SBAR();
    // P5
    LOAD_A(1, 0); LOAD_B(1, 0);
    stageA(0, 1, kx);
    SBAR();
    MMA_QUAD(0, 0);
    SBAR();
    // P6
    LOAD_B(1, 1);
    stageB(0, 1, kx);
    SBAR();
    MMA_QUAD(0, 1);
    SBAR();
    // P7
    LOAD_A(1, 1);
    stageA(1, 0, ky);
    SBAR();
    MMA_QUAD(1, 0);
    SBAR();
    // P8
    stageB(1, 0, ky);
    SBAR();
    MMA_QUAD(1, 1);
    if (t < NITER - 1) { asm volatile("s_waitcnt vmcnt(4)" ::: "memory"); }
    else               { asm volatile("s_waitcnt vmcnt(0)" ::: "memory"); }
    __builtin_amdgcn_sched_barrier(0);
    SBAR();
  }

  // ---- in-register epilogue: acc[f][g] = gate g of unit bn*64+wn*16+r15 ----
  const int unit = bn * 64 + wn * 16 + r15;
  const float b0 = bias[unit];
  const float b1 = bias[1024 + unit];
  const float b2 = bias[2048 + unit];
  const float b3 = bias[3072 + unit];
  #pragma unroll
  for (int f = 0; f < 8; ++f) {
    const int row0 = brow + f * 32 + wm * 16 + kh * 4;
    #pragma unroll
    for (int j = 0; j < 4; ++j) {
      size_t gidx = (size_t)(row0 + j) * UNITS + unit;
      float zi = acc[f][0][j] + b0;
      float zf = acc[f][1][j] + b1;
      float zc = acc[f][2][j] + b2;
      float zo = acc[f][3][j] + b3;
      float ig = sigmoid_f(zi);
      float fg = sigmoid_f(zf);
      float gg = tanh_f(zc);
      float og = sigmoid_f(zo);
      float cn = fg * c_in[gidx] + ig * gg;
      float hn = og * tanh_f(cn);
      out_h[gidx] = hn;
      out_c[gidx] = cn;
    }
  }
}

extern "C" void kernel_launch(void* const* d_in, const int* in_sizes, int n_in,
                              void* d_out, int out_size, void* d_ws, size_t ws_size,
                              hipStream_t stream) {
  const float* x     = (const float*)d_in[0];
  const float* h     = (const float*)d_in[1];
  const float* c     = (const float*)d_in[2];
  const float* kern  = (const float*)d_in[3];
  const float* rkern = (const float*)d_in[4];
  const float* bias  = (const float*)d_in[5];
  const float* dp    = (const float*)d_in[6];
  const float* rdp   = (const float*)d_in[7];
  const float* kdp   = (const float*)d_in[8];
  const float* rkdp  = (const float*)d_in[9];

  unsigned short* Abf  = (unsigned short*)d_ws;                       // 32MB
  unsigned short* Btbf = Abf + (size_t)B_ROWS * KTOT;                 // 16MB

  float* out_h = (float*)d_out;
  float* out_c = out_h + (size_t)B_ROWS * UNITS;

  prep_a_kernel<<<2048, 256, 0, stream>>>(x, h, dp, rdp, Abf);
  prep_b_kernel<<<dim3(128, 64), dim3(32, 8), 0, stream>>>(kern, rkern, kdp, rkdp, Btbf);
  lstm_gemm_kernel<<<512, 512, 0, stream>>>(Abf, Btbf, bias, c, out_h, out_c);
}

// Round 5
// 194.156 us; speedup vs baseline: 1.2394x; 1.0020x over previous
//
#include <hip/hip_runtime.h>

#define B_ROWS 8192
#define DIN    1024
#define UNITS  1024
#define KTOT   2048   // DIN + UNITS
#define NCOLS  4096   // 4*UNITS
#define BM 256
#define BN 256
#define BK 64
#define NT (KTOT / BK)    // 32 K-tiles
#define NITER (NT / 2)    // 16 iterations, 2 K-tiles each

typedef __attribute__((ext_vector_type(8))) short bf16x8;
typedef __attribute__((ext_vector_type(4))) float f32x4;
typedef __attribute__((ext_vector_type(4))) unsigned short u16x4;

#define AS1(p) ((const __attribute__((address_space(1))) void*)(p))
#define AS3(p) ((__attribute__((address_space(3))) void*)(p))

__device__ inline unsigned short f2bf(float v) {
  union { float f; unsigned int u; } un; un.f = v;
  unsigned int r = un.u + 0x7FFFu + ((un.u >> 16) & 1u);   // RNE
  return (unsigned short)(r >> 16);
}

// XOR-swizzle within each 64-element K-tile group, baked into the STORED
// global layout (rule #21: global_load_lds stays linear; ds_read applies
// the same XOR).
__device__ inline int swz_col(int c, int r) {
  return (c & ~63) | ((c & 63) ^ ((r & 7) << 3));
}

__device__ inline float sigmoid_f(float x) { return 1.0f / (1.0f + __expf(-x)); }
__device__ inline float tanh_f(float x)    { return 1.0f - 2.0f / (1.0f + __expf(2.0f * x)); }

// ---------------- prep A: A_bf16[row][k] = masked x (k<1024) | masked h (k>=1024) ----
__global__ void prep_a_kernel(const float* __restrict__ x, const float* __restrict__ h,
                              const float* __restrict__ dp, const float* __restrict__ rdp,
                              unsigned short* __restrict__ A) {
  const int n4 = (B_ROWS * DIN) / 4;
  const float sc = 1.0f / 0.9f;
  for (int i = blockIdx.x * blockDim.x + threadIdx.x; i < n4; i += gridDim.x * blockDim.x) {
    float4 xv = reinterpret_cast<const float4*>(x)[i];
    float4 uv = reinterpret_cast<const float4*>(dp)[i];
    float4 hv = reinterpret_cast<const float4*>(h)[i];
    float4 rv = reinterpret_cast<const float4*>(rdp)[i];
    u16x4 xa, ha;
    xa.x = f2bf(uv.x >= 0.1f ? xv.x * sc : 0.0f);
    xa.y = f2bf(uv.y >= 0.1f ? xv.y * sc : 0.0f);
    xa.z = f2bf(uv.z >= 0.1f ? xv.z * sc : 0.0f);
    xa.w = f2bf(uv.w >= 0.1f ? xv.w * sc : 0.0f);
    ha.x = f2bf(rv.x >= 0.1f ? hv.x * sc : 0.0f);
    ha.y = f2bf(rv.y >= 0.1f ? hv.y * sc : 0.0f);
    ha.z = f2bf(rv.z >= 0.1f ? hv.z * sc : 0.0f);
    ha.w = f2bf(rv.w >= 0.1f ? hv.w * sc : 0.0f);
    int e = i * 4;
    int row = e >> 10;
    int col = e & 1023;
    int csw = swz_col(col, row);
    *reinterpret_cast<u16x4*>(&A[(size_t)row * KTOT + csw]) = xa;
    *reinterpret_cast<u16x4*>(&A[(size_t)row * KTOT + DIN + csw]) = ha;
  }
}

// ---------------- prep B: Bt[n][k] (bf16, N-major), 64-unit gate interleave ---------
// source col c = g*1024 + m  ->  n = (m>>6)*256 + g*64 + (m&63)
__global__ void prep_b_kernel(const float* __restrict__ kern, const float* __restrict__ rkern,
                              const float* __restrict__ kdp, const float* __restrict__ rkdp,
                              unsigned short* __restrict__ Bt) {
  __shared__ float tile[32][33];
  const int c0 = blockIdx.x * 32;
  const int k0 = blockIdx.y * 32;
  const float sc = 1.0f / 0.95f;
  const float* W; const float* U; int kr;
  if (k0 < DIN) { W = kern;  U = kdp;  kr = k0; }
  else          { W = rkern; U = rkdp; kr = k0 - DIN; }
  const int tx = threadIdx.x, ty = threadIdx.y;
  #pragma unroll
  for (int i = 0; i < 4; ++i) {
    int kk = ty + i * 8;
    size_t off = (size_t)(kr + kk) * NCOLS + c0 + tx;
    float wv = W[off];
    float uv = U[off];
    tile[kk][tx] = (uv >= 0.05f) ? wv * sc : 0.0f;
  }
  __syncthreads();
  const int g  = c0 >> 10;
  const int m0 = c0 & 1023;
  #pragma unroll
  for (int i = 0; i < 4; ++i) {
    int cc = ty + i * 8;
    int m = m0 + cc;
    int n = (m >> 6) * 256 + g * 64 + (m & 63);
    int kst = swz_col(k0 + tx, n);
    Bt[(size_t)n * KTOT + kst] = f2bf(tile[tx][cc]);
  }
}

// ---------------- 256x256 8-phase GEMM, template-exact stage discipline -------------
// One half-tile (16KB, 2 global_load_lds/thread) staged per phase; 7 halves in
// flight steady-state; vmcnt(6) at P4/P8 (vmcnt(0) in the last iteration, whose
// stages are skipped).
// Iteration t (buf0 tile 2t, buf1 tile 2t+1), kx=2t+2, ky=2t+3:
//  P1 rd A0,B0(b0) | st A1(b1,2t+1)  [A1 b1 dead since prev P7]
//  P2 rd B1(b0)    | st A0(b0,kx)    [read P1]
//  P3 rd A1(b0)    | st B0(b0,kx)    [read P1]
//  P4 -            | st B1(b0,kx)    [read P2]  | vmcnt(6): drains prevP6,prevP7,prevP8,P1
//                                               = ALL of buf1 tile 2t+1 for P5..P7
//  P5 rd A0,B0(b1) | st A1(b0,kx)    [read P3]
//  P6 rd B1(b1)    | st A0(b1,ky)    [read P5]
//  P7 rd A1(b1)    | st B0(b1,ky)    [read P5]
//  P8 -            | st B1(b1,ky)    [read P6]  | vmcnt(6): drains P2,P3,P4,P5
//                                               = ALL of buf0 tile kx for next P1..P3

#define FENCE() asm volatile("" ::: "memory")
#define SBAR()  do { FENCE(); __builtin_amdgcn_s_barrier(); FENCE(); } while (0)

#define LOAD_A(BUF, MH) do { \
  const unsigned short* as_ = (const unsigned short*)(smem + (BUF) * 65536); \
  _Pragma("unroll") for (int f_ = 0; f_ < 4; ++f_) { \
    const int row_ = ((MH) * 4 + f_) * 32 + wm * 16 + r15; \
    _Pragma("unroll") for (int ks_ = 0; ks_ < 2; ++ks_) \
      a[f_ * 2 + ks_] = *(const bf16x8*)(&as_[row_ * 64 + ((ks_ * 32 + kh * 8) ^ sw)]); \
  } } while (0)

#define LOAD_B(BUF, NH) do { \
  const unsigned short* bs_ = (const unsigned short*)(smem + (BUF) * 65536 + 32768); \
  _Pragma("unroll") for (int g_ = 0; g_ < 2; ++g_) { \
    const int row_ = ((NH) * 2 + g_) * 64 + wn * 16 + r15; \
    _Pragma("unroll") for (int ks_ = 0; ks_ < 2; ++ks_) \
      b[((NH) * 2 + g_) * 2 + ks_] = *(const bf16x8*)(&bs_[row_ * 64 + ((ks_ * 32 + kh * 8) ^ sw)]); \
  } } while (0)

#define MMA_QUAD(MH, NH) do { \
  __builtin_amdgcn_s_setprio(1); \
  _Pragma("unroll") for (int f_ = 0; f_ < 4; ++f_) \
    _Pragma("unroll") for (int g_ = 0; g_ < 2; ++g_) \
      _Pragma("unroll") for (int ks_ = 0; ks_ < 2; ++ks_) \
        acc[(MH) * 4 + f_][(NH) * 2 + g_] = __builtin_amdgcn_mfma_f32_16x16x32_bf16( \
            a[f_ * 2 + ks_], b[((NH) * 2 + g_) * 2 + ks_], acc[(MH) * 4 + f_][(NH) * 2 + g_], 0, 0, 0); \
  __builtin_amdgcn_s_setprio(0); \
  } while (0)

#define VM_WAIT(T) do { \
  if ((T) < NITER - 1) { asm volatile("s_waitcnt vmcnt(6)" ::: "memory"); } \
  else                 { asm volatile("s_waitcnt vmcnt(0)" ::: "memory"); } \
  __builtin_amdgcn_sched_barrier(0); \
  } while (0)

__global__ __launch_bounds__(512, 2) void lstm_gemm_kernel(
    const unsigned short* __restrict__ A,
    const unsigned short* __restrict__ Bt,
    const float* __restrict__ bias,
    const float* __restrict__ c_in,
    float* __restrict__ out_h,
    float* __restrict__ out_c) {
  __shared__ __align__(16) unsigned char smem[131072];

  const int tid  = threadIdx.x;
  const int lane = tid & 63;
  const int wid  = tid >> 6;     // 0..7
  const int wm   = wid & 1;      // M-wave (16-row interleave)
  const int wn   = wid >> 1;     // 0..3  (16-col interleave)
  const int bm   = blockIdx.x >> 4;   // 32 row-blocks
  const int bn   = blockIdx.x & 15;   // 16 col-blocks
  const int brow = bm * BM;
  const int bnrow = bn * BN;
  const int r15  = lane & 15;
  const int kh   = lane >> 4;
  const int sw   = (r15 & 7) << 3;

  f32x4 acc[8][4];
  const f32x4 zero4 = {0.0f, 0.0f, 0.0f, 0.0f};
  #pragma unroll
  for (int i = 0; i < 8; ++i)
    #pragma unroll
    for (int j = 0; j < 4; ++j) acc[i][j] = zero4;
  bf16x8 a[8], b[8];

  // one stage = one 16KB half-tile = 2 x global_load_lds(16B) per thread
  auto stageA = [&](int buf, int half, int kt) {
    if (kt >= NT) return;
    const int k0 = kt * BK;
    #pragma unroll
    for (int r = 0; r < 2; ++r) {
      const int rowb = half * 128 + r * 64 + wid * 8;   // wave-uniform
      const unsigned short* g = A + (size_t)(brow + rowb + (lane >> 3)) * KTOT + k0 + (lane & 7) * 8;
      __builtin_amdgcn_global_load_lds(AS1(g), AS3(smem + buf * 65536 + rowb * 128), 16, 0, 0);
    }
  };
  auto stageB = [&](int buf, int half, int kt) {
    if (kt >= NT) return;
    const int k0 = kt * BK;
    #pragma unroll
    for (int r = 0; r < 2; ++r) {
      const int rowb = half * 128 + r * 64 + wid * 8;
      const unsigned short* g = Bt + (size_t)(bnrow + rowb + (lane >> 3)) * KTOT + k0 + (lane & 7) * 8;
      __builtin_amdgcn_global_load_lds(AS1(g), AS3(smem + buf * 65536 + 32768 + rowb * 128), 16, 0, 0);
    }
  };

  // prologue: buf0 tile0 all 4 halves FIRST (drained by vmcnt(6)), then 3 of buf1 tile1
  stageA(0, 0, 0); stageB(0, 0, 0); stageB(0, 1, 0); stageA(0, 1, 0);
  stageA(1, 0, 1); stageB(1, 0, 1); stageB(1, 1, 1);
  asm volatile("s_waitcnt vmcnt(6)" ::: "memory");
  __builtin_amdgcn_sched_barrier(0);
  SBAR();

  #pragma unroll 1
  for (int t = 0; t < NITER; ++t) {
    const int kx = 2 * t + 2;      // next buf0 tile
    const int ky = 2 * t + 3;      // next buf1 tile
    // P1
    LOAD_A(0, 0); LOAD_B(0, 0);
    stageA(1, 1, 2 * t + 1);
    SBAR();
    MMA_QUAD(0, 0);
    SBAR();
    // P2
    LOAD_B(0, 1);
    stageA(0, 0, kx);
    SBAR();
    MMA_QUAD(0, 1);
    SBAR();
    // P3
    LOAD_A(0, 1);
    stageB(0, 0, kx);
    SBAR();
    MMA_QUAD(1, 0);
    SBAR();
    // P4
    stageB(0, 1, kx);
    SBAR();
    MMA_QUAD(1, 1);
    VM_WAIT(t);
    SBAR();
    // P5
    LOAD_A(1, 0); LOAD_B(1, 0);
    stageA(0, 1, kx);
    SBAR();
    MMA_QUAD(0, 0);
    SBAR();
    // P6
    LOAD_B(1, 1);
    stageA(1, 0, ky);
    SBAR();
    MMA_QUAD(0, 1);
    SBAR();
    // P7
    LOAD_A(1, 1);
    stageB(1, 0, ky);
    SBAR();
    MMA_QUAD(1, 0);
    SBAR();
    // P8
    stageB(1, 1, ky);
    SBAR();
    MMA_QUAD(1, 1);
    VM_WAIT(t);
    SBAR();
  }

  // ---- in-register epilogue: acc[f][g] = gate g of unit bn*64+wn*16+r15 ----
  const int unit = bn * 64 + wn * 16 + r15;
  const float b0 = bias[unit];
  const float b1 = bias[1024 + unit];
  const float b2 = bias[2048 + unit];
  const float b3 = bias[3072 + unit];
  #pragma unroll
  for (int f = 0; f < 8; ++f) {
    const int row0 = brow + f * 32 + wm * 16 + kh * 4;
    #pragma unroll
    for (int j = 0; j < 4; ++j) {
      size_t gidx = (size_t)(row0 + j) * UNITS + unit;
      float zi = acc[f][0][j] + b0;
      float zf = acc[f][1][j] + b1;
      float zc = acc[f][2][j] + b2;
      float zo = acc[f][3][j] + b3;
      float ig = sigmoid_f(zi);
      float fg = sigmoid_f(zf);
      float gg = tanh_f(zc);
      float og = sigmoid_f(zo);
      float cn = fg * c_in[gidx] + ig * gg;
      float hn = og * tanh_f(cn);
      out_h[gidx] = hn;
      out_c[gidx] = cn;
    }
  }
}

extern "C" void kernel_launch(void* const* d_in, const int* in_sizes, int n_in,
                              void* d_out, int out_size, void* d_ws, size_t ws_size,
                              hipStream_t stream) {
  const float* x     = (const float*)d_in[0];
  const float* h     = (const float*)d_in[1];
  const float* c     = (const float*)d_in[2];
  const float* kern  = (const float*)d_in[3];
  const float* rkern = (const float*)d_in[4];
  const float* bias  = (const float*)d_in[5];
  const float* dp    = (const float*)d_in[6];
  const float* rdp   = (const float*)d_in[7];
  const float* kdp   = (const float*)d_in[8];
  const float* rkdp  = (const float*)d_in[9];

  unsigned short* Abf  = (unsigned short*)d_ws;                       // 32MB
  unsigned short* Btbf = Abf + (size_t)B_ROWS * KTOT;                 // 16MB

  float* out_h = (float*)d_out;
  float* out_c = out_h + (size_t)B_ROWS * UNITS;

  prep_a_kernel<<<2048, 256, 0, stream>>>(x, h, dp, rdp, Abf);
  prep_b_kernel<<<dim3(128, 64), dim3(32, 8), 0, stream>>>(kern, rkern, kdp, rkdp, Btbf);
  lstm_gemm_kernel<<<512, 512, 0, stream>>>(Abf, Btbf, bias, c, out_h, out_c);
}